// Round 2
// baseline (718.234 us; speedup 1.0000x reference)
//
#include <hip/hip_runtime.h>

typedef unsigned short u16;
typedef short bf16x8 __attribute__((ext_vector_type(8)));
typedef float f32x4 __attribute__((ext_vector_type(4)));

__device__ __forceinline__ u16 f2bf(float f) {
  union { float f; unsigned u; } v; v.f = f;
  unsigned r = v.u + 0x7fffu + ((v.u >> 16) & 1u);
  return (u16)(r >> 16);
}

#define MFMA_B16(a, b, c) __builtin_amdgcn_mfma_f32_16x16x32_bf16((a), (b), (c), 0, 0, 0)

// ---------------- K0: fp32 -> bf16 conversion (x and the 3 weights) ----------------
__global__ void __launch_bounds__(256) convert_kernel(
    const float* __restrict__ x, const float* __restrict__ Wq,
    const float* __restrict__ Wk, const float* __restrict__ Wv,
    u16* __restrict__ xb, u16* __restrict__ Wb) {
  int i = blockIdx.x * 256 + threadIdx.x;   // one float4 per thread
  const int NX4 = 2097152;                  // 8388608/4
  if (i < NX4) {
    const float4 v = ((const float4*)x)[i];
    ushort4 o; o.x = f2bf(v.x); o.y = f2bf(v.y); o.z = f2bf(v.z); o.w = f2bf(v.w);
    ((ushort4*)xb)[i] = o;
  } else {
    int j4 = i - NX4;                       // [0, 49152)
    int j = j4 * 4;                         // [0, 196608)
    const float* W = (j < 65536) ? Wq : ((j < 131072) ? Wk : Wv);
    const float4 v = *(const float4*)(W + (j & 65535));
    ushort4 o; o.x = f2bf(v.x); o.y = f2bf(v.y); o.z = f2bf(v.z); o.w = f2bf(v.w);
    ((ushort4*)Wb)[j4] = o;
  }
}

// ---------------- K1: linear (x @ W.T + b) with permute-scatter epilogue ----------------
// A = xb [32768 x 256], Bt = Wb [768 x 256] (rows = out features, NT gemm)
// out feature j: w = j>>8 (q/k/v), jj = j&255, h = jj>>5, e = jj&31
// row m: rx = m>>11, c = m&2047; h2 = c>>8, c2 = (c&255)*8+h, d2 = rx*32+e
// q,k -> permuted fp32 [8][2048][512]; v -> transposed bf16 [8][512][2048]
__global__ void __launch_bounds__(256) linear_kernel(
    const u16* __restrict__ xb, const u16* __restrict__ Wb,
    const float* __restrict__ bq, const float* __restrict__ bk, const float* __restrict__ bv,
    float* __restrict__ q_lin, float* __restrict__ k_lin, u16* __restrict__ vT) {
  __shared__ __align__(16) u16 As[128 * 64];
  __shared__ __align__(16) u16 Bs[64 * 64];
  const int tid = threadIdx.x;
  const int m0 = blockIdx.x * 128, n0 = blockIdx.y * 64;
  const int wave = tid >> 6, lane = tid & 63;
  const int wm = wave >> 1, wn = wave & 1;
  const int lrow = lane & 15, lk = lane >> 4;
  const f32x4 fzero = {0.f, 0.f, 0.f, 0.f};
  f32x4 acc[4][2];
  for (int a = 0; a < 4; ++a) for (int b = 0; b < 2; ++b) acc[a][b] = fzero;

  for (int k0 = 0; k0 < 256; k0 += 64) {
    __syncthreads();
    for (int p = 0; p < 4; ++p) {          // A tile 128x64
      int idx = p * 256 + tid, row = idx >> 3, g8 = idx & 7;
      *(int4*)(As + row * 64 + ((g8 ^ (row & 7)) * 8)) =
          *(const int4*)(xb + (size_t)(m0 + row) * 256 + k0 + g8 * 8);
    }
    for (int p = 0; p < 2; ++p) {          // B tile 64x64
      int idx = p * 256 + tid, row = idx >> 3, g8 = idx & 7;
      *(int4*)(Bs + row * 64 + ((g8 ^ (row & 7)) * 8)) =
          *(const int4*)(Wb + (size_t)(n0 + row) * 256 + k0 + g8 * 8);
    }
    __syncthreads();
    for (int ks = 0; ks < 2; ++ks) {
      bf16x8 a[4], b[2];
      for (int f = 0; f < 4; ++f) {
        int r = wm * 64 + f * 16 + lrow;
        a[f] = *(const bf16x8*)(As + r * 64 + (((ks * 4 + lk) ^ (r & 7)) * 8));
      }
      for (int f = 0; f < 2; ++f) {
        int r = wn * 32 + f * 16 + lrow;
        b[f] = *(const bf16x8*)(Bs + r * 64 + (((ks * 4 + lk) ^ (r & 7)) * 8));
      }
      for (int fm = 0; fm < 4; ++fm)
        for (int fn = 0; fn < 2; ++fn)
          acc[fm][fn] = MFMA_B16(a[fm], b[fn], acc[fm][fn]);
    }
  }
  for (int fm = 0; fm < 4; ++fm)
    for (int fn = 0; fn < 2; ++fn)
      for (int r = 0; r < 4; ++r) {
        int grow = wm * 64 + fm * 16 + lk * 4 + r;
        int gcol = wn * 32 + fn * 16 + lrow;
        int m = m0 + grow, j = n0 + gcol;
        int rx = m >> 11, c = m & 2047;
        int w = j >> 8, jj = j & 255, h = jj >> 5, e = jj & 31;
        int h2 = c >> 8, c2 = ((c & 255) << 3) + h, d2 = (rx << 5) + e;
        float bias = (w == 0) ? bq[jj] : ((w == 1) ? bk[jj] : bv[jj]);
        float val = acc[fm][fn][r] + bias;
        size_t qk_off = ((size_t)((h2 << 11) + c2) << 9) + d2;
        if (w == 0)      q_lin[qk_off] = val;
        else if (w == 1) k_lin[qk_off] = val;
        else             vT[(((size_t)(h2 << 9) + d2) << 11) + c2] = f2bf(val);
      }
}

// ---------------- K2: softmax over d (512) per (h,n) row; fold *sqrt(512) ----------------
__global__ void __launch_bounds__(256) softmax_q_kernel(
    const float* __restrict__ q_lin, u16* __restrict__ qb) {
  const int row = blockIdx.x, tid = threadIdx.x;
  const int wave = tid >> 6, lane = tid & 63;
  const float* src = q_lin + ((size_t)row << 9);
  float v0 = src[tid], v1 = src[tid + 256];
  float m = fmaxf(v0, v1);
  for (int o = 32; o; o >>= 1) m = fmaxf(m, __shfl_xor(m, o));
  __shared__ float red[8];
  if (lane == 0) red[wave] = m;
  __syncthreads();
  m = fmaxf(fmaxf(red[0], red[1]), fmaxf(red[2], red[3]));
  float e0 = expf(v0 - m), e1 = expf(v1 - m);
  float s = e0 + e1;
  for (int o = 32; o; o >>= 1) s += __shfl_xor(s, o);
  if (lane == 0) red[4 + wave] = s;
  __syncthreads();
  s = red[4] + red[5] + red[6] + red[7];
  float sc = 22.627416997969522f / s;
  u16* dst = qb + ((size_t)row << 9);
  dst[tid] = f2bf(e0 * sc);
  dst[tid + 256] = f2bf(e1 * sc);
}

// ---------------- K3: softmax over n (2048) per (h,d) column; write kb and kT ----------------
__global__ void __launch_bounds__(256) softmax_k_kernel(
    const float* __restrict__ k_lin, u16* __restrict__ kb, u16* __restrict__ kT) {
  const int tid = threadIdx.x;
  const int dl = tid & 63, ng = tid >> 6;
  const int h = blockIdx.y;
  const int d = blockIdx.x * 64 + dl;
  const float* base = k_lin + ((size_t)h << 20) + d;
  float m = -3.0e38f;
  for (int n = ng; n < 2048; n += 4) m = fmaxf(m, base[(size_t)n << 9]);
  __shared__ float red[4][64];
  red[ng][dl] = m;
  __syncthreads();
  m = fmaxf(fmaxf(red[0][dl], red[1][dl]), fmaxf(red[2][dl], red[3][dl]));
  __syncthreads();
  float s = 0.f;
  for (int n = ng; n < 2048; n += 4) s += expf(base[(size_t)n << 9] - m);
  red[ng][dl] = s;
  __syncthreads();
  s = red[0][dl] + red[1][dl] + red[2][dl] + red[3][dl];
  float inv = 1.0f / s;
  u16* kbp = kb + ((size_t)h << 20) + d;
  u16* kTp = kT + ((size_t)h << 20) + ((size_t)d << 11);
  for (int n = ng; n < 2048; n += 4) {
    float e = expf(base[(size_t)n << 9] - m) * inv;
    u16 b = f2bf(e);
    kbp[(size_t)n << 9] = b;
    kTp[n] = b;
  }
}

// ---------------- K4: attn[h,n,m] = sum_d qb[h,n,d]*kb[h,m,d]  (NT, K=512) ----------------
__global__ void __launch_bounds__(256) attn_kernel(
    const u16* __restrict__ qb, const u16* __restrict__ kb, float* __restrict__ attn) {
  __shared__ __align__(16) u16 As[128 * 64];
  __shared__ __align__(16) u16 Bs[128 * 64];
  const int tid = threadIdx.x, h = blockIdx.z;
  const int n0 = blockIdx.x * 128, mm0 = blockIdx.y * 128;
  const u16* A = qb + ((size_t)h << 20);
  const u16* B = kb + ((size_t)h << 20);
  const int wave = tid >> 6, lane = tid & 63;
  const int wm = wave >> 1, wn = wave & 1;
  const int lrow = lane & 15, lk = lane >> 4;
  const f32x4 fzero = {0.f, 0.f, 0.f, 0.f};
  f32x4 acc[4][4];
  for (int a = 0; a < 4; ++a) for (int b = 0; b < 4; ++b) acc[a][b] = fzero;

  for (int k0 = 0; k0 < 512; k0 += 64) {
    __syncthreads();
    for (int p = 0; p < 4; ++p) {
      int idx = p * 256 + tid, row = idx >> 3, g8 = idx & 7;
      int dst = row * 64 + ((g8 ^ (row & 7)) * 8);
      *(int4*)(As + dst) = *(const int4*)(A + (size_t)(n0 + row) * 512 + k0 + g8 * 8);
      *(int4*)(Bs + dst) = *(const int4*)(B + (size_t)(mm0 + row) * 512 + k0 + g8 * 8);
    }
    __syncthreads();
    for (int ks = 0; ks < 2; ++ks) {
      bf16x8 a[4], b[4];
      for (int f = 0; f < 4; ++f) {
        int r = wm * 64 + f * 16 + lrow;
        a[f] = *(const bf16x8*)(As + r * 64 + (((ks * 4 + lk) ^ (r & 7)) * 8));
      }
      for (int f = 0; f < 4; ++f) {
        int r = wn * 64 + f * 16 + lrow;
        b[f] = *(const bf16x8*)(Bs + r * 64 + (((ks * 4 + lk) ^ (r & 7)) * 8));
      }
      for (int fm = 0; fm < 4; ++fm)
        for (int fn = 0; fn < 4; ++fn)
          acc[fm][fn] = MFMA_B16(a[fm], b[fn], acc[fm][fn]);
    }
  }
  float* dst = attn + ((size_t)h << 22);
  for (int fm = 0; fm < 4; ++fm)
    for (int fn = 0; fn < 4; ++fn)
      for (int r = 0; r < 4; ++r) {
        int row = n0 + wm * 64 + fm * 16 + lk * 4 + r;
        int col = mm0 + wn * 64 + fn * 16 + lrow;
        dst[((size_t)row << 11) + col] = acc[fm][fn][r];
      }
}

// ---------------- K5: ctxT[h,e,d] = sum_n vT[h,e,n]*kT[h,d,n]  (NT, K=2048) ----------------
__global__ void __launch_bounds__(256) ctx_kernel(
    const u16* __restrict__ vT, const u16* __restrict__ kT, u16* __restrict__ ctxT) {
  __shared__ __align__(16) u16 As[128 * 64];
  __shared__ __align__(16) u16 Bs[128 * 64];
  const int tid = threadIdx.x, h = blockIdx.z;
  const int e0 = blockIdx.x * 128, d0 = blockIdx.y * 128;
  const u16* A = vT + ((size_t)h << 20);
  const u16* B = kT + ((size_t)h << 20);
  const int wave = tid >> 6, lane = tid & 63;
  const int wm = wave >> 1, wn = wave & 1;
  const int lrow = lane & 15, lk = lane >> 4;
  const f32x4 fzero = {0.f, 0.f, 0.f, 0.f};
  f32x4 acc[4][4];
  for (int a = 0; a < 4; ++a) for (int b = 0; b < 4; ++b) acc[a][b] = fzero;

  for (int k0 = 0; k0 < 2048; k0 += 64) {
    __syncthreads();
    for (int p = 0; p < 4; ++p) {
      int idx = p * 256 + tid, row = idx >> 3, g8 = idx & 7;
      int dst = row * 64 + ((g8 ^ (row & 7)) * 8);
      *(int4*)(As + dst) = *(const int4*)(A + (size_t)(e0 + row) * 2048 + k0 + g8 * 8);
      *(int4*)(Bs + dst) = *(const int4*)(B + (size_t)(d0 + row) * 2048 + k0 + g8 * 8);
    }
    __syncthreads();
    for (int ks = 0; ks < 2; ++ks) {
      bf16x8 a[4], b[4];
      for (int f = 0; f < 4; ++f) {
        int r = wm * 64 + f * 16 + lrow;
        a[f] = *(const bf16x8*)(As + r * 64 + (((ks * 4 + lk) ^ (r & 7)) * 8));
      }
      for (int f = 0; f < 4; ++f) {
        int r = wn * 64 + f * 16 + lrow;
        b[f] = *(const bf16x8*)(Bs + r * 64 + (((ks * 4 + lk) ^ (r & 7)) * 8));
      }
      for (int fm = 0; fm < 4; ++fm)
        for (int fn = 0; fn < 4; ++fn)
          acc[fm][fn] = MFMA_B16(a[fm], b[fn], acc[fm][fn]);
    }
  }
  u16* dst = ctxT + ((size_t)h << 18);
  for (int fm = 0; fm < 4; ++fm)
    for (int fn = 0; fn < 4; ++fn)
      for (int r = 0; r < 4; ++r) {
        int erow = e0 + wm * 64 + fm * 16 + lk * 4 + r;
        int dcol = d0 + wn * 64 + fn * 16 + lrow;
        dst[((size_t)erow << 9) + dcol] = f2bf(acc[fm][fn][r]);
      }
}

// ---------------- K6: out[h,n,e] = sum_d qb[h,n,d]*ctxT[h,e,d] (NT, K=512) + inverse permute ----------------
__global__ void __launch_bounds__(256) out_kernel(
    const u16* __restrict__ qb, const u16* __restrict__ ctxT, float* __restrict__ out) {
  __shared__ __align__(16) u16 As[128 * 64];
  __shared__ __align__(16) u16 Bs[128 * 64];
  const int tid = threadIdx.x, h = blockIdx.z;
  const int n0 = blockIdx.x * 128, e0 = blockIdx.y * 128;
  const u16* A = qb + ((size_t)h << 20);
  const u16* B = ctxT + ((size_t)h << 18);
  const int wave = tid >> 6, lane = tid & 63;
  const int wm = wave >> 1, wn = wave & 1;
  const int lrow = lane & 15, lk = lane >> 4;
  const f32x4 fzero = {0.f, 0.f, 0.f, 0.f};
  f32x4 acc[4][4];
  for (int a = 0; a < 4; ++a) for (int b = 0; b < 4; ++b) acc[a][b] = fzero;

  for (int k0 = 0; k0 < 512; k0 += 64) {
    __syncthreads();
    for (int p = 0; p < 4; ++p) {
      int idx = p * 256 + tid, row = idx >> 3, g8 = idx & 7;
      int dst = row * 64 + ((g8 ^ (row & 7)) * 8);
      *(int4*)(As + dst) = *(const int4*)(A + (size_t)(n0 + row) * 512 + k0 + g8 * 8);
      *(int4*)(Bs + dst) = *(const int4*)(B + (size_t)(e0 + row) * 512 + k0 + g8 * 8);
    }
    __syncthreads();
    for (int ks = 0; ks < 2; ++ks) {
      bf16x8 a[4], b[4];
      for (int f = 0; f < 4; ++f) {
        int r = wm * 64 + f * 16 + lrow;
        a[f] = *(const bf16x8*)(As + r * 64 + (((ks * 4 + lk) ^ (r & 7)) * 8));
      }
      for (int f = 0; f < 4; ++f) {
        int r = wn * 64 + f * 16 + lrow;
        b[f] = *(const bf16x8*)(Bs + r * 64 + (((ks * 4 + lk) ^ (r & 7)) * 8));
      }
      for (int fm = 0; fm < 4; ++fm)
        for (int fn = 0; fn < 4; ++fn)
          acc[fm][fn] = MFMA_B16(a[fm], b[fn], acc[fm][fn]);
    }
  }
  for (int fm = 0; fm < 4; ++fm)
    for (int fn = 0; fn < 4; ++fn)
      for (int r = 0; r < 4; ++r) {
        int n = n0 + wm * 64 + fm * 16 + lk * 4 + r;
        int e = e0 + wn * 64 + fn * 16 + lrow;
        // final: out[rx][n][h*32 + el] with rx=e>>5, el=e&31
        size_t dstIdx = ((size_t)(((e >> 5) << 11) + n) << 8) + (h << 5) + (e & 31);
        out[dstIdx] = acc[fm][fn][r];
      }
}

extern "C" void kernel_launch(void* const* d_in, const int* in_sizes, int n_in,
                              void* d_out, int out_size, void* d_ws, size_t ws_size,
                              hipStream_t stream) {
  const float* x  = (const float*)d_in[0];
  const float* Wq = (const float*)d_in[1];
  const float* bq = (const float*)d_in[2];
  const float* Wk = (const float*)d_in[3];
  const float* bk = (const float*)d_in[4];
  const float* Wv = (const float*)d_in[5];
  const float* bv = (const float*)d_in[6];
  float* out  = (float*)d_out;
  float* attn = out + 8388608;

  char* ws = (char*)d_ws;
  u16*   xb    = (u16*)(ws);                      // 16,777,216 B
  u16*   Wb    = (u16*)(ws + 16777216);           //    393,216 B
  float* q_lin = (float*)(ws + 17170432);         // 33,554,432 B
  float* k_lin = (float*)(ws + 50724864);         // 33,554,432 B
  u16*   vT    = (u16*)(ws + 84279296);           // 16,777,216 B  (peak = 101,056,512 B)
  // reuse after producers are dead:
  u16*   qb    = (u16*)(ws);                      // over xb   (dead after K1)
  u16*   kb    = (u16*)(ws + 17170432);           // over q_lin (dead after K2)
  u16*   kT    = (u16*)(ws + 33947648);
  u16*   ctxT  = (u16*)(ws + 50724864);           // over k_lin (dead after K3)

  convert_kernel<<<8384, 256, 0, stream>>>(x, Wq, Wk, Wv, xb, Wb);
  linear_kernel<<<dim3(256, 12), 256, 0, stream>>>(xb, Wb, bq, bk, bv, q_lin, k_lin, vT);
  softmax_q_kernel<<<16384, 256, 0, stream>>>(q_lin, qb);
  softmax_k_kernel<<<dim3(8, 8), 256, 0, stream>>>(k_lin, kb, kT);
  attn_kernel<<<dim3(16, 16, 8), 256, 0, stream>>>(qb, kb, attn);
  ctx_kernel<<<dim3(4, 4, 8), 256, 0, stream>>>(vT, kT, ctxT);
  out_kernel<<<dim3(16, 4, 8), 256, 0, stream>>>(qb, ctxT, out);
}

// Round 3
// 392.181 us; speedup vs baseline: 1.8314x; 1.8314x over previous
//
#include <hip/hip_runtime.h>

typedef unsigned short u16;
typedef short bf16x8 __attribute__((ext_vector_type(8)));
typedef float f32x4 __attribute__((ext_vector_type(4)));

__device__ __forceinline__ u16 f2bf(float f) {
  union { float f; unsigned u; } v; v.f = f;
  unsigned r = v.u + 0x7fffu + ((v.u >> 16) & 1u);
  return (u16)(r >> 16);
}

#define MFMA_B16(a, b, c) __builtin_amdgcn_mfma_f32_16x16x32_bf16((a), (b), (c), 0, 0, 0)

// ---------------- K0: fp32 -> bf16 conversion (x and the 3 weights) ----------------
__global__ void __launch_bounds__(256) convert_kernel(
    const float* __restrict__ x, const float* __restrict__ Wq,
    const float* __restrict__ Wk, const float* __restrict__ Wv,
    u16* __restrict__ xb, u16* __restrict__ Wb) {
  int i = blockIdx.x * 256 + threadIdx.x;   // one float4 per thread
  const int NX4 = 2097152;                  // 8388608/4
  if (i < NX4) {
    const float4 v = ((const float4*)x)[i];
    ushort4 o; o.x = f2bf(v.x); o.y = f2bf(v.y); o.z = f2bf(v.z); o.w = f2bf(v.w);
    ((ushort4*)xb)[i] = o;
  } else {
    int j4 = i - NX4;                       // [0, 49152)
    int j = j4 * 4;                         // [0, 196608)
    const float* W = (j < 65536) ? Wq : ((j < 131072) ? Wk : Wv);
    const float4 v = *(const float4*)(W + (j & 65535));
    ushort4 o; o.x = f2bf(v.x); o.y = f2bf(v.y); o.z = f2bf(v.z); o.w = f2bf(v.w);
    ((ushort4*)Wb)[j4] = o;
  }
}

// ---------------- K1: linear (x @ W.T + b) with permute-scatter epilogue ----------------
__global__ void __launch_bounds__(256) linear_kernel(
    const u16* __restrict__ xb, const u16* __restrict__ Wb,
    const float* __restrict__ bq, const float* __restrict__ bk, const float* __restrict__ bv,
    float* __restrict__ q_lin, float* __restrict__ k_lin, u16* __restrict__ vT) {
  __shared__ __align__(16) u16 As[128 * 64];
  __shared__ __align__(16) u16 Bs[64 * 64];
  const int tid = threadIdx.x;
  const int m0 = blockIdx.x * 128, n0 = blockIdx.y * 64;
  const int wave = tid >> 6, lane = tid & 63;
  const int wm = wave >> 1, wn = wave & 1;
  const int lrow = lane & 15, lk = lane >> 4;
  const f32x4 fzero = {0.f, 0.f, 0.f, 0.f};
  f32x4 acc[4][2];
  for (int a = 0; a < 4; ++a) for (int b = 0; b < 2; ++b) acc[a][b] = fzero;

  for (int k0 = 0; k0 < 256; k0 += 64) {
    __syncthreads();
    for (int p = 0; p < 4; ++p) {          // A tile 128x64
      int idx = p * 256 + tid, row = idx >> 3, g8 = idx & 7;
      *(int4*)(As + row * 64 + ((g8 ^ (row & 7)) * 8)) =
          *(const int4*)(xb + (size_t)(m0 + row) * 256 + k0 + g8 * 8);
    }
    for (int p = 0; p < 2; ++p) {          // B tile 64x64
      int idx = p * 256 + tid, row = idx >> 3, g8 = idx & 7;
      *(int4*)(Bs + row * 64 + ((g8 ^ (row & 7)) * 8)) =
          *(const int4*)(Wb + (size_t)(n0 + row) * 256 + k0 + g8 * 8);
    }
    __syncthreads();
    for (int ks = 0; ks < 2; ++ks) {
      bf16x8 a[4], b[2];
      for (int f = 0; f < 4; ++f) {
        int r = wm * 64 + f * 16 + lrow;
        a[f] = *(const bf16x8*)(As + r * 64 + (((ks * 4 + lk) ^ (r & 7)) * 8));
      }
      for (int f = 0; f < 2; ++f) {
        int r = wn * 32 + f * 16 + lrow;
        b[f] = *(const bf16x8*)(Bs + r * 64 + (((ks * 4 + lk) ^ (r & 7)) * 8));
      }
      for (int fm = 0; fm < 4; ++fm)
        for (int fn = 0; fn < 2; ++fn)
          acc[fm][fn] = MFMA_B16(a[fm], b[fn], acc[fm][fn]);
    }
  }
  for (int fm = 0; fm < 4; ++fm)
    for (int fn = 0; fn < 2; ++fn)
      for (int r = 0; r < 4; ++r) {
        int grow = wm * 64 + fm * 16 + lk * 4 + r;
        int gcol = wn * 32 + fn * 16 + lrow;
        int m = m0 + grow, j = n0 + gcol;
        int rx = m >> 11, c = m & 2047;
        int w = j >> 8, jj = j & 255, h = jj >> 5, e = jj & 31;
        int h2 = c >> 8, c2 = ((c & 255) << 3) + h, d2 = (rx << 5) + e;
        float bias = (w == 0) ? bq[jj] : ((w == 1) ? bk[jj] : bv[jj]);
        float val = acc[fm][fn][r] + bias;
        size_t qk_off = ((size_t)((h2 << 11) + c2) << 9) + d2;
        if (w == 0)      q_lin[qk_off] = val;
        else if (w == 1) k_lin[qk_off] = val;
        else             vT[(((size_t)(h2 << 9) + d2) << 11) + c2] = f2bf(val);
      }
}

// ---------------- K2: softmax over d (512) per (h,n) row; fold *sqrt(512) ----------------
__global__ void __launch_bounds__(256) softmax_q_kernel(
    const float* __restrict__ q_lin, u16* __restrict__ qb) {
  const int row = blockIdx.x, tid = threadIdx.x;
  const int wave = tid >> 6, lane = tid & 63;
  const float* src = q_lin + ((size_t)row << 9);
  float v0 = src[tid], v1 = src[tid + 256];
  float m = fmaxf(v0, v1);
  for (int o = 32; o; o >>= 1) m = fmaxf(m, __shfl_xor(m, o));
  __shared__ float red[8];
  if (lane == 0) red[wave] = m;
  __syncthreads();
  m = fmaxf(fmaxf(red[0], red[1]), fmaxf(red[2], red[3]));
  float e0 = expf(v0 - m), e1 = expf(v1 - m);
  float s = e0 + e1;
  for (int o = 32; o; o >>= 1) s += __shfl_xor(s, o);
  if (lane == 0) red[4 + wave] = s;
  __syncthreads();
  s = red[4] + red[5] + red[6] + red[7];
  float sc = 22.627416997969522f / s;
  u16* dst = qb + ((size_t)row << 9);
  dst[tid] = f2bf(e0 * sc);
  dst[tid + 256] = f2bf(e1 * sc);
}

// ---------------- K3a: per-chunk partial (max, sum-exp) over n for each (h,d) column ----------------
// grid (8 dtile, 8 h, 16 nchunk) x 256. Each thread: 32 rows in registers.
__global__ void __launch_bounds__(256) softmax_k_part_kernel(
    const float* __restrict__ k_lin, float2* __restrict__ partials) {
  const int tid = threadIdx.x;
  const int dl = tid & 63, ng = tid >> 6;
  const int dt = blockIdx.x, h = blockIdx.y, nch = blockIdx.z;
  const int d = dt * 64 + dl;
  const float* base = k_lin + ((size_t)h << 20) + ((size_t)(nch * 128 + ng * 32) << 9) + d;
  float v[32];
  #pragma unroll
  for (int i = 0; i < 32; ++i) v[i] = base[(size_t)i << 9];
  float m = v[0];
  #pragma unroll
  for (int i = 1; i < 32; ++i) m = fmaxf(m, v[i]);
  __shared__ float2 red[4][64];
  red[ng][dl].x = m;
  __syncthreads();
  float M = fmaxf(fmaxf(red[0][dl].x, red[1][dl].x), fmaxf(red[2][dl].x, red[3][dl].x));
  float s = 0.f;
  #pragma unroll
  for (int i = 0; i < 32; ++i) s += __expf(v[i] - M);
  red[ng][dl].y = s;
  __syncthreads();
  if (ng == 0) {
    float S = red[0][dl].y + red[1][dl].y + red[2][dl].y + red[3][dl].y;
    partials[(((h * 8 + dt) * 16 + nch) << 6) + dl] = make_float2(M, S);
  }
}

// ---------------- K3c: combine partials, normalize, write kb (coalesced) + kT (LDS transpose) ----------------
__global__ void __launch_bounds__(256) softmax_k_norm_kernel(
    const float* __restrict__ k_lin, const float2* __restrict__ partials,
    u16* __restrict__ kb, u16* __restrict__ kT) {
  __shared__ __align__(16) u16 Ts[64 * 128];   // [d][n] tile, XOR-swizzled at 8-u16 granularity
  const int tid = threadIdx.x;
  const int dl = tid & 63, ng = tid >> 6;
  const int dt = blockIdx.x, h = blockIdx.y, nch = blockIdx.z;
  const int d0 = dt * 64, n0 = nch * 128;
  // combine the 16 chunk partials for column d0+dl
  const float2* pb = partials + (((h * 8 + dt) * 16) << 6) + dl;
  float2 pj[16];
  float M = -3.0e38f;
  #pragma unroll
  for (int j = 0; j < 16; ++j) { pj[j] = pb[j << 6]; M = fmaxf(M, pj[j].x); }
  float S = 0.f;
  #pragma unroll
  for (int j = 0; j < 16; ++j) S += pj[j].y * __expf(pj[j].x - M);
  float inv = 1.0f / S;
  // normalize 32 contiguous rows, write kb, stash bf16 into register vectors
  const float* src = k_lin + ((size_t)h << 20) + ((size_t)(n0 + ng * 32) << 9) + d0 + dl;
  u16* kbp = kb + ((size_t)h << 20) + ((size_t)(n0 + ng * 32) << 9) + d0 + dl;
  bf16x8 pk[4];
  #pragma unroll
  for (int i = 0; i < 32; ++i) {
    float e = __expf(src[(size_t)i << 9] - M) * inv;
    u16 b = f2bf(e);
    kbp[(size_t)i << 9] = b;
    pk[i >> 3][i & 7] = (short)b;
  }
  // stage into LDS (write: row dl, 16B slot nl8, slot XOR-swizzled by row)
  #pragma unroll
  for (int j = 0; j < 4; ++j) {
    int nl8 = ng * 4 + j;
    *(bf16x8*)(Ts + dl * 128 + (((nl8 * 8) ^ ((dl & 7) << 3)))) = pk[j];
  }
  __syncthreads();
  // read transposed rows, vector-store to kT
  const int rd = tid >> 2;
  u16* kTp = kT + ((size_t)h << 20) + ((size_t)(d0 + rd) << 11) + n0;
  #pragma unroll
  for (int j = 0; j < 4; ++j) {
    int g = (tid & 3) + j * 4;
    bf16x8 vv = *(const bf16x8*)(Ts + rd * 128 + (((g * 8) ^ ((rd & 7) << 3))));
    *(bf16x8*)(kTp + g * 8) = vv;
  }
}

// ---------------- K4: attn[h,n,m] = sum_d qb[h,n,d]*kb[h,m,d]  (NT, K=512) ----------------
__global__ void __launch_bounds__(256) attn_kernel(
    const u16* __restrict__ qb, const u16* __restrict__ kb, float* __restrict__ attn) {
  __shared__ __align__(16) u16 As[128 * 64];
  __shared__ __align__(16) u16 Bs[128 * 64];
  const int tid = threadIdx.x, h = blockIdx.z;
  const int n0 = blockIdx.x * 128, mm0 = blockIdx.y * 128;
  const u16* A = qb + ((size_t)h << 20);
  const u16* B = kb + ((size_t)h << 20);
  const int wave = tid >> 6, lane = tid & 63;
  const int wm = wave >> 1, wn = wave & 1;
  const int lrow = lane & 15, lk = lane >> 4;
  const f32x4 fzero = {0.f, 0.f, 0.f, 0.f};
  f32x4 acc[4][4];
  for (int a = 0; a < 4; ++a) for (int b = 0; b < 4; ++b) acc[a][b] = fzero;

  for (int k0 = 0; k0 < 512; k0 += 64) {
    __syncthreads();
    for (int p = 0; p < 4; ++p) {
      int idx = p * 256 + tid, row = idx >> 3, g8 = idx & 7;
      int dst = row * 64 + ((g8 ^ (row & 7)) * 8);
      *(int4*)(As + dst) = *(const int4*)(A + (size_t)(n0 + row) * 512 + k0 + g8 * 8);
      *(int4*)(Bs + dst) = *(const int4*)(B + (size_t)(mm0 + row) * 512 + k0 + g8 * 8);
    }
    __syncthreads();
    for (int ks = 0; ks < 2; ++ks) {
      bf16x8 a[4], b[4];
      for (int f = 0; f < 4; ++f) {
        int r = wm * 64 + f * 16 + lrow;
        a[f] = *(const bf16x8*)(As + r * 64 + (((ks * 4 + lk) ^ (r & 7)) * 8));
      }
      for (int f = 0; f < 4; ++f) {
        int r = wn * 64 + f * 16 + lrow;
        b[f] = *(const bf16x8*)(Bs + r * 64 + (((ks * 4 + lk) ^ (r & 7)) * 8));
      }
      for (int fm = 0; fm < 4; ++fm)
        for (int fn = 0; fn < 4; ++fn)
          acc[fm][fn] = MFMA_B16(a[fm], b[fn], acc[fm][fn]);
    }
  }
  float* dst = attn + ((size_t)h << 22);
  for (int fm = 0; fm < 4; ++fm)
    for (int fn = 0; fn < 4; ++fn)
      for (int r = 0; r < 4; ++r) {
        int row = n0 + wm * 64 + fm * 16 + lk * 4 + r;
        int col = mm0 + wn * 64 + fn * 16 + lrow;
        dst[((size_t)row << 11) + col] = acc[fm][fn][r];
      }
}

// ---------------- K5: ctxT[h,e,d] = sum_n vT[h,e,n]*kT[h,d,n]  (NT, K=2048) ----------------
__global__ void __launch_bounds__(256) ctx_kernel(
    const u16* __restrict__ vT, const u16* __restrict__ kT, u16* __restrict__ ctxT) {
  __shared__ __align__(16) u16 As[128 * 64];
  __shared__ __align__(16) u16 Bs[128 * 64];
  const int tid = threadIdx.x, h = blockIdx.z;
  const int e0 = blockIdx.x * 128, d0 = blockIdx.y * 128;
  const u16* A = vT + ((size_t)h << 20);
  const u16* B = kT + ((size_t)h << 20);
  const int wave = tid >> 6, lane = tid & 63;
  const int wm = wave >> 1, wn = wave & 1;
  const int lrow = lane & 15, lk = lane >> 4;
  const f32x4 fzero = {0.f, 0.f, 0.f, 0.f};
  f32x4 acc[4][4];
  for (int a = 0; a < 4; ++a) for (int b = 0; b < 4; ++b) acc[a][b] = fzero;

  for (int k0 = 0; k0 < 2048; k0 += 64) {
    __syncthreads();
    for (int p = 0; p < 4; ++p) {
      int idx = p * 256 + tid, row = idx >> 3, g8 = idx & 7;
      int dst = row * 64 + ((g8 ^ (row & 7)) * 8);
      *(int4*)(As + dst) = *(const int4*)(A + (size_t)(e0 + row) * 2048 + k0 + g8 * 8);
      *(int4*)(Bs + dst) = *(const int4*)(B + (size_t)(d0 + row) * 2048 + k0 + g8 * 8);
    }
    __syncthreads();
    for (int ks = 0; ks < 2; ++ks) {
      bf16x8 a[4], b[4];
      for (int f = 0; f < 4; ++f) {
        int r = wm * 64 + f * 16 + lrow;
        a[f] = *(const bf16x8*)(As + r * 64 + (((ks * 4 + lk) ^ (r & 7)) * 8));
      }
      for (int f = 0; f < 4; ++f) {
        int r = wn * 64 + f * 16 + lrow;
        b[f] = *(const bf16x8*)(Bs + r * 64 + (((ks * 4 + lk) ^ (r & 7)) * 8));
      }
      for (int fm = 0; fm < 4; ++fm)
        for (int fn = 0; fn < 4; ++fn)
          acc[fm][fn] = MFMA_B16(a[fm], b[fn], acc[fm][fn]);
    }
  }
  u16* dst = ctxT + ((size_t)h << 18);
  for (int fm = 0; fm < 4; ++fm)
    for (int fn = 0; fn < 4; ++fn)
      for (int r = 0; r < 4; ++r) {
        int erow = e0 + wm * 64 + fm * 16 + lk * 4 + r;
        int dcol = d0 + wn * 64 + fn * 16 + lrow;
        dst[((size_t)erow << 9) + dcol] = f2bf(acc[fm][fn][r]);
      }
}

// ---------------- K6: out[h,n,e] = sum_d qb[h,n,d]*ctxT[h,e,d] (NT, K=512) + inverse permute ----------------
__global__ void __launch_bounds__(256) out_kernel(
    const u16* __restrict__ qb, const u16* __restrict__ ctxT, float* __restrict__ out) {
  __shared__ __align__(16) u16 As[128 * 64];
  __shared__ __align__(16) u16 Bs[128 * 64];
  const int tid = threadIdx.x, h = blockIdx.z;
  const int n0 = blockIdx.x * 128, e0 = blockIdx.y * 128;
  const u16* A = qb + ((size_t)h << 20);
  const u16* B = ctxT + ((size_t)h << 18);
  const int wave = tid >> 6, lane = tid & 63;
  const int wm = wave >> 1, wn = wave & 1;
  const int lrow = lane & 15, lk = lane >> 4;
  const f32x4 fzero = {0.f, 0.f, 0.f, 0.f};
  f32x4 acc[4][4];
  for (int a = 0; a < 4; ++a) for (int b = 0; b < 4; ++b) acc[a][b] = fzero;

  for (int k0 = 0; k0 < 512; k0 += 64) {
    __syncthreads();
    for (int p = 0; p < 4; ++p) {
      int idx = p * 256 + tid, row = idx >> 3, g8 = idx & 7;
      int dst = row * 64 + ((g8 ^ (row & 7)) * 8);
      *(int4*)(As + dst) = *(const int4*)(A + (size_t)(n0 + row) * 512 + k0 + g8 * 8);
      *(int4*)(Bs + dst) = *(const int4*)(B + (size_t)(e0 + row) * 512 + k0 + g8 * 8);
    }
    __syncthreads();
    for (int ks = 0; ks < 2; ++ks) {
      bf16x8 a[4], b[4];
      for (int f = 0; f < 4; ++f) {
        int r = wm * 64 + f * 16 + lrow;
        a[f] = *(const bf16x8*)(As + r * 64 + (((ks * 4 + lk) ^ (r & 7)) * 8));
      }
      for (int f = 0; f < 4; ++f) {
        int r = wn * 64 + f * 16 + lrow;
        b[f] = *(const bf16x8*)(Bs + r * 64 + (((ks * 4 + lk) ^ (r & 7)) * 8));
      }
      for (int fm = 0; fm < 4; ++fm)
        for (int fn = 0; fn < 4; ++fn)
          acc[fm][fn] = MFMA_B16(a[fm], b[fn], acc[fm][fn]);
    }
  }
  for (int fm = 0; fm < 4; ++fm)
    for (int fn = 0; fn < 4; ++fn)
      for (int r = 0; r < 4; ++r) {
        int n = n0 + wm * 64 + fm * 16 + lk * 4 + r;
        int e = e0 + wn * 64 + fn * 16 + lrow;
        // final: out[rx][n][h*32 + el] with rx=e>>5, el=e&31
        size_t dstIdx = ((size_t)(((e >> 5) << 11) + n) << 8) + (h << 5) + (e & 31);
        out[dstIdx] = acc[fm][fn][r];
      }
}

extern "C" void kernel_launch(void* const* d_in, const int* in_sizes, int n_in,
                              void* d_out, int out_size, void* d_ws, size_t ws_size,
                              hipStream_t stream) {
  const float* x  = (const float*)d_in[0];
  const float* Wq = (const float*)d_in[1];
  const float* bq = (const float*)d_in[2];
  const float* Wk = (const float*)d_in[3];
  const float* bk = (const float*)d_in[4];
  const float* Wv = (const float*)d_in[5];
  const float* bv = (const float*)d_in[6];
  float* out  = (float*)d_out;
  float* attn = out + 8388608;

  char* ws = (char*)d_ws;
  u16*   xb    = (u16*)(ws);                      // 16,777,216 B
  u16*   Wb    = (u16*)(ws + 16777216);           //    393,216 B
  float* q_lin = (float*)(ws + 17170432);         // 33,554,432 B
  float* k_lin = (float*)(ws + 50724864);         // 33,554,432 B
  u16*   vT    = (u16*)(ws + 84279296);           // 16,777,216 B  (peak = 101,056,512 B)
  // reuse after producers are dead:
  u16*   qb    = (u16*)(ws);                      // over xb   (dead after K1)
  u16*   kb    = (u16*)(ws + 17170432);           // over q_lin (dead after K2)
  u16*   kT    = (u16*)(ws + 33947648);
  u16*   ctxT  = (u16*)(ws + 50724864);           // over k_lin (dead after K3)
  // softmax-k partials: park in the tail of the attn output region
  // (8*8*16*64 float2 = 512 KB); attn_kernel overwrites it afterwards.
  float2* partials = (float2*)(attn + 33554432 - 131072);

  convert_kernel<<<8384, 256, 0, stream>>>(x, Wq, Wk, Wv, xb, Wb);
  linear_kernel<<<dim3(256, 12), 256, 0, stream>>>(xb, Wb, bq, bk, bv, q_lin, k_lin, vT);
  softmax_q_kernel<<<16384, 256, 0, stream>>>(q_lin, qb);
  softmax_k_part_kernel<<<dim3(8, 8, 16), 256, 0, stream>>>(k_lin, partials);
  softmax_k_norm_kernel<<<dim3(8, 8, 16), 256, 0, stream>>>(k_lin, partials, kb, kT);
  attn_kernel<<<dim3(16, 16, 8), 256, 0, stream>>>(qb, kb, attn);
  ctx_kernel<<<dim3(4, 4, 8), 256, 0, stream>>>(vT, kT, ctxT);
  out_kernel<<<dim3(16, 4, 8), 256, 0, stream>>>(qb, ctxT, out);
}

// Round 4
// 384.659 us; speedup vs baseline: 1.8672x; 1.0196x over previous
//
#include <hip/hip_runtime.h>

typedef unsigned short u16;
typedef short bf16x8 __attribute__((ext_vector_type(8)));
typedef float f32x4 __attribute__((ext_vector_type(4)));

__device__ __forceinline__ u16 f2bf(float f) {
  union { float f; unsigned u; } v; v.f = f;
  unsigned r = v.u + 0x7fffu + ((v.u >> 16) & 1u);
  return (u16)(r >> 16);
}

#define MFMA_B16(a, b, c) __builtin_amdgcn_mfma_f32_16x16x32_bf16((a), (b), (c), 0, 0, 0)

// Stage a (CHUNKS*8) x 64-u16 tile global->LDS via global_load_lds width=16.
// LDS layout is the XOR-swizzled layout: LDS[row][slot] = global[row][slot ^ (row&7)]
// achieved by pre-swizzling the per-lane GLOBAL source (rule 21 / m173):
// gload_lds writes lane l's 16B to ldsbase + l*16 (linear), so lane l covers
// row = chunk*8 + (l>>3), slot = l&7, and must READ global slot (l&7)^(row&7).
template<int CHUNKS>
__device__ __forceinline__ void stage_tile(const u16* __restrict__ gbase, int ldg,
                                           u16* lds, int tid) {
  const int wave = tid >> 6, lane = tid & 63;
  const int r8 = lane >> 3, slot = lane & 7;
#pragma unroll
  for (int j = 0; j < CHUNKS / 4; ++j) {
    const int chunk = wave + j * 4;
    const int row = chunk * 8 + r8;
    const u16* g = gbase + (size_t)row * ldg + (((slot ^ (row & 7)) << 3));
    __builtin_amdgcn_global_load_lds(
        (const __attribute__((address_space(1))) void*)g,
        (__attribute__((address_space(3))) void*)(lds + chunk * 512),
        16, 0, 0);
  }
}

// ---------------- K0: fp32 -> bf16 conversion (x and the 3 weights) ----------------
__global__ void __launch_bounds__(256) convert_kernel(
    const float* __restrict__ x, const float* __restrict__ Wq,
    const float* __restrict__ Wk, const float* __restrict__ Wv,
    u16* __restrict__ xb, u16* __restrict__ Wb) {
  int i = blockIdx.x * 256 + threadIdx.x;   // one float4 per thread
  const int NX4 = 2097152;                  // 8388608/4
  if (i < NX4) {
    const float4 v = ((const float4*)x)[i];
    ushort4 o; o.x = f2bf(v.x); o.y = f2bf(v.y); o.z = f2bf(v.z); o.w = f2bf(v.w);
    ((ushort4*)xb)[i] = o;
  } else {
    int j4 = i - NX4;                       // [0, 49152)
    int j = j4 * 4;                         // [0, 196608)
    const float* W = (j < 65536) ? Wq : ((j < 131072) ? Wk : Wv);
    const float4 v = *(const float4*)(W + (j & 65535));
    ushort4 o; o.x = f2bf(v.x); o.y = f2bf(v.y); o.z = f2bf(v.z); o.w = f2bf(v.w);
    ((ushort4*)Wb)[j4] = o;
  }
}

// ---------------- K1: linear (x @ W.T + b) with permute-scatter epilogue ----------------
__global__ void __launch_bounds__(256) linear_kernel(
    const u16* __restrict__ xb, const u16* __restrict__ Wb,
    const float* __restrict__ bq, const float* __restrict__ bk, const float* __restrict__ bv,
    float* __restrict__ q_lin, float* __restrict__ k_lin, u16* __restrict__ vT) {
  __shared__ __align__(16) u16 As[128 * 64];
  __shared__ __align__(16) u16 Bs[64 * 64];
  const int tid = threadIdx.x;
  const int m0 = blockIdx.x * 128, n0 = blockIdx.y * 64;
  const int wave = tid >> 6, lane = tid & 63;
  const int wm = wave >> 1, wn = wave & 1;
  const int lrow = lane & 15, lk = lane >> 4;
  const f32x4 fzero = {0.f, 0.f, 0.f, 0.f};
  f32x4 acc[4][2];
  for (int a = 0; a < 4; ++a) for (int b = 0; b < 2; ++b) acc[a][b] = fzero;

  for (int k0 = 0; k0 < 256; k0 += 64) {
    __syncthreads();
    stage_tile<16>(xb + (size_t)m0 * 256 + k0, 256, As, tid);
    stage_tile<8>(Wb + (size_t)n0 * 256 + k0, 256, Bs, tid);
    __syncthreads();
    for (int ks = 0; ks < 2; ++ks) {
      bf16x8 a[4], b[2];
      for (int f = 0; f < 4; ++f) {
        int r = wm * 64 + f * 16 + lrow;
        a[f] = *(const bf16x8*)(As + r * 64 + (((ks * 4 + lk) ^ (r & 7)) * 8));
      }
      for (int f = 0; f < 2; ++f) {
        int r = wn * 32 + f * 16 + lrow;
        b[f] = *(const bf16x8*)(Bs + r * 64 + (((ks * 4 + lk) ^ (r & 7)) * 8));
      }
      for (int fm = 0; fm < 4; ++fm)
        for (int fn = 0; fn < 2; ++fn)
          acc[fm][fn] = MFMA_B16(a[fm], b[fn], acc[fm][fn]);
    }
  }
  for (int fm = 0; fm < 4; ++fm)
    for (int fn = 0; fn < 2; ++fn)
      for (int r = 0; r < 4; ++r) {
        int grow = wm * 64 + fm * 16 + lk * 4 + r;
        int gcol = wn * 32 + fn * 16 + lrow;
        int m = m0 + grow, j = n0 + gcol;
        int rx = m >> 11, c = m & 2047;
        int w = j >> 8, jj = j & 255, h = jj >> 5, e = jj & 31;
        int h2 = c >> 8, c2 = ((c & 255) << 3) + h, d2 = (rx << 5) + e;
        float bias = (w == 0) ? bq[jj] : ((w == 1) ? bk[jj] : bv[jj]);
        float val = acc[fm][fn][r] + bias;
        size_t qk_off = ((size_t)((h2 << 11) + c2) << 9) + d2;
        if (w == 0)      q_lin[qk_off] = val;
        else if (w == 1) k_lin[qk_off] = val;
        else             vT[(((size_t)(h2 << 9) + d2) << 11) + c2] = f2bf(val);
      }
}

// ---------------- K2: softmax over d (512) per (h,n) row; fold *sqrt(512) ----------------
__global__ void __launch_bounds__(256) softmax_q_kernel(
    const float* __restrict__ q_lin, u16* __restrict__ qb) {
  const int row = blockIdx.x, tid = threadIdx.x;
  const int wave = tid >> 6, lane = tid & 63;
  const float* src = q_lin + ((size_t)row << 9);
  float v0 = src[tid], v1 = src[tid + 256];
  float m = fmaxf(v0, v1);
  for (int o = 32; o; o >>= 1) m = fmaxf(m, __shfl_xor(m, o));
  __shared__ float red[8];
  if (lane == 0) red[wave] = m;
  __syncthreads();
  m = fmaxf(fmaxf(red[0], red[1]), fmaxf(red[2], red[3]));
  float e0 = expf(v0 - m), e1 = expf(v1 - m);
  float s = e0 + e1;
  for (int o = 32; o; o >>= 1) s += __shfl_xor(s, o);
  if (lane == 0) red[4 + wave] = s;
  __syncthreads();
  s = red[4] + red[5] + red[6] + red[7];
  float sc = 22.627416997969522f / s;
  u16* dst = qb + ((size_t)row << 9);
  dst[tid] = f2bf(e0 * sc);
  dst[tid + 256] = f2bf(e1 * sc);
}

// ---------------- K3a: per-chunk partial (max, sum-exp) over n for each (h,d) column ----------------
__global__ void __launch_bounds__(256) softmax_k_part_kernel(
    const float* __restrict__ k_lin, float2* __restrict__ partials) {
  const int tid = threadIdx.x;
  const int dl = tid & 63, ng = tid >> 6;
  const int dt = blockIdx.x, h = blockIdx.y, nch = blockIdx.z;
  const int d = dt * 64 + dl;
  const float* base = k_lin + ((size_t)h << 20) + ((size_t)(nch * 128 + ng * 32) << 9) + d;
  float v[32];
  #pragma unroll
  for (int i = 0; i < 32; ++i) v[i] = base[(size_t)i << 9];
  float m = v[0];
  #pragma unroll
  for (int i = 1; i < 32; ++i) m = fmaxf(m, v[i]);
  __shared__ float2 red[4][64];
  red[ng][dl].x = m;
  __syncthreads();
  float M = fmaxf(fmaxf(red[0][dl].x, red[1][dl].x), fmaxf(red[2][dl].x, red[3][dl].x));
  float s = 0.f;
  #pragma unroll
  for (int i = 0; i < 32; ++i) s += __expf(v[i] - M);
  red[ng][dl].y = s;
  __syncthreads();
  if (ng == 0) {
    float S = red[0][dl].y + red[1][dl].y + red[2][dl].y + red[3][dl].y;
    partials[(((h * 8 + dt) * 16 + nch) << 6) + dl] = make_float2(M, S);
  }
}

// ---------------- K3c: combine partials, normalize, write kb (coalesced) + kT (LDS transpose) ----------------
__global__ void __launch_bounds__(256) softmax_k_norm_kernel(
    const float* __restrict__ k_lin, const float2* __restrict__ partials,
    u16* __restrict__ kb, u16* __restrict__ kT) {
  __shared__ __align__(16) u16 Ts[64 * 128];   // [d][n] tile, XOR-swizzled at 8-u16 granularity
  const int tid = threadIdx.x;
  const int dl = tid & 63, ng = tid >> 6;
  const int dt = blockIdx.x, h = blockIdx.y, nch = blockIdx.z;
  const int d0 = dt * 64, n0 = nch * 128;
  const float2* pb = partials + (((h * 8 + dt) * 16) << 6) + dl;
  float2 pj[16];
  float M = -3.0e38f;
  #pragma unroll
  for (int j = 0; j < 16; ++j) { pj[j] = pb[j << 6]; M = fmaxf(M, pj[j].x); }
  float S = 0.f;
  #pragma unroll
  for (int j = 0; j < 16; ++j) S += pj[j].y * __expf(pj[j].x - M);
  float inv = 1.0f / S;
  const float* src = k_lin + ((size_t)h << 20) + ((size_t)(n0 + ng * 32) << 9) + d0 + dl;
  u16* kbp = kb + ((size_t)h << 20) + ((size_t)(n0 + ng * 32) << 9) + d0 + dl;
  bf16x8 pk[4];
  #pragma unroll
  for (int i = 0; i < 32; ++i) {
    float e = __expf(src[(size_t)i << 9] - M) * inv;
    u16 b = f2bf(e);
    kbp[(size_t)i << 9] = b;
    pk[i >> 3][i & 7] = (short)b;
  }
  #pragma unroll
  for (int j = 0; j < 4; ++j) {
    int nl8 = ng * 4 + j;
    *(bf16x8*)(Ts + dl * 128 + (((nl8 * 8) ^ ((dl & 7) << 3)))) = pk[j];
  }
  __syncthreads();
  const int rd = tid >> 2;
  u16* kTp = kT + ((size_t)h << 20) + ((size_t)(d0 + rd) << 11) + n0;
  #pragma unroll
  for (int j = 0; j < 4; ++j) {
    int g = (tid & 3) + j * 4;
    bf16x8 vv = *(const bf16x8*)(Ts + rd * 128 + (((g * 8) ^ ((rd & 7) << 3))));
    *(bf16x8*)(kTp + g * 8) = vv;
  }
}

// ---------------- K4: attn[h,n,m] = sum_d qb[h,n,d]*kb[h,m,d]  (NT, K=512) ----------------
__global__ void __launch_bounds__(256) attn_kernel(
    const u16* __restrict__ qb, const u16* __restrict__ kb, float* __restrict__ attn) {
  __shared__ __align__(16) u16 As[128 * 64];
  __shared__ __align__(16) u16 Bs[128 * 64];
  const int tid = threadIdx.x, h = blockIdx.z;
  const int n0 = blockIdx.x * 128, mm0 = blockIdx.y * 128;
  const u16* A = qb + ((size_t)h << 20);
  const u16* B = kb + ((size_t)h << 20);
  const int wave = tid >> 6, lane = tid & 63;
  const int wm = wave >> 1, wn = wave & 1;
  const int lrow = lane & 15, lk = lane >> 4;
  const f32x4 fzero = {0.f, 0.f, 0.f, 0.f};
  f32x4 acc[4][4];
  for (int a = 0; a < 4; ++a) for (int b = 0; b < 4; ++b) acc[a][b] = fzero;

  for (int k0 = 0; k0 < 512; k0 += 64) {
    __syncthreads();
    stage_tile<16>(A + (size_t)n0 * 512 + k0, 512, As, tid);
    stage_tile<16>(B + (size_t)mm0 * 512 + k0, 512, Bs, tid);
    __syncthreads();
    for (int ks = 0; ks < 2; ++ks) {
      bf16x8 a[4], b[4];
      for (int f = 0; f < 4; ++f) {
        int r = wm * 64 + f * 16 + lrow;
        a[f] = *(const bf16x8*)(As + r * 64 + (((ks * 4 + lk) ^ (r & 7)) * 8));
      }
      for (int f = 0; f < 4; ++f) {
        int r = wn * 64 + f * 16 + lrow;
        b[f] = *(const bf16x8*)(Bs + r * 64 + (((ks * 4 + lk) ^ (r & 7)) * 8));
      }
      for (int fm = 0; fm < 4; ++fm)
        for (int fn = 0; fn < 4; ++fn)
          acc[fm][fn] = MFMA_B16(a[fm], b[fn], acc[fm][fn]);
    }
  }
  float* dst = attn + ((size_t)h << 22);
  for (int fm = 0; fm < 4; ++fm)
    for (int fn = 0; fn < 4; ++fn)
      for (int r = 0; r < 4; ++r) {
        int row = n0 + wm * 64 + fm * 16 + lk * 4 + r;
        int col = mm0 + wn * 64 + fn * 16 + lrow;
        dst[((size_t)row << 11) + col] = acc[fm][fn][r];
      }
}

// ---------------- K5: ctxT[h,e,d] = sum_n vT[h,e,n]*kT[h,d,n]  (NT, K=2048) ----------------
__global__ void __launch_bounds__(256) ctx_kernel(
    const u16* __restrict__ vT, const u16* __restrict__ kT, u16* __restrict__ ctxT) {
  __shared__ __align__(16) u16 As[128 * 64];
  __shared__ __align__(16) u16 Bs[128 * 64];
  const int tid = threadIdx.x, h = blockIdx.z;
  const int e0 = blockIdx.x * 128, d0 = blockIdx.y * 128;
  const u16* A = vT + ((size_t)h << 20);
  const u16* B = kT + ((size_t)h << 20);
  const int wave = tid >> 6, lane = tid & 63;
  const int wm = wave >> 1, wn = wave & 1;
  const int lrow = lane & 15, lk = lane >> 4;
  const f32x4 fzero = {0.f, 0.f, 0.f, 0.f};
  f32x4 acc[4][4];
  for (int a = 0; a < 4; ++a) for (int b = 0; b < 4; ++b) acc[a][b] = fzero;

  for (int k0 = 0; k0 < 2048; k0 += 64) {
    __syncthreads();
    stage_tile<16>(A + (size_t)e0 * 2048 + k0, 2048, As, tid);
    stage_tile<16>(B + (size_t)d0 * 2048 + k0, 2048, Bs, tid);
    __syncthreads();
    for (int ks = 0; ks < 2; ++ks) {
      bf16x8 a[4], b[4];
      for (int f = 0; f < 4; ++f) {
        int r = wm * 64 + f * 16 + lrow;
        a[f] = *(const bf16x8*)(As + r * 64 + (((ks * 4 + lk) ^ (r & 7)) * 8));
      }
      for (int f = 0; f < 4; ++f) {
        int r = wn * 64 + f * 16 + lrow;
        b[f] = *(const bf16x8*)(Bs + r * 64 + (((ks * 4 + lk) ^ (r & 7)) * 8));
      }
      for (int fm = 0; fm < 4; ++fm)
        for (int fn = 0; fn < 4; ++fn)
          acc[fm][fn] = MFMA_B16(a[fm], b[fn], acc[fm][fn]);
    }
  }
  u16* dst = ctxT + ((size_t)h << 18);
  for (int fm = 0; fm < 4; ++fm)
    for (int fn = 0; fn < 4; ++fn)
      for (int r = 0; r < 4; ++r) {
        int erow = e0 + wm * 64 + fm * 16 + lk * 4 + r;
        int dcol = d0 + wn * 64 + fn * 16 + lrow;
        dst[((size_t)erow << 9) + dcol] = f2bf(acc[fm][fn][r]);
      }
}

// ---------------- K6: out[h,n,e] = sum_d qb[h,n,d]*ctxT[h,e,d] (NT, K=512) + inverse permute ----------------
__global__ void __launch_bounds__(256) out_kernel(
    const u16* __restrict__ qb, const u16* __restrict__ ctxT, float* __restrict__ out) {
  __shared__ __align__(16) u16 As[128 * 64];
  __shared__ __align__(16) u16 Bs[128 * 64];
  const int tid = threadIdx.x, h = blockIdx.z;
  const int n0 = blockIdx.x * 128, e0 = blockIdx.y * 128;
  const u16* A = qb + ((size_t)h << 20);
  const u16* B = ctxT + ((size_t)h << 18);
  const int wave = tid >> 6, lane = tid & 63;
  const int wm = wave >> 1, wn = wave & 1;
  const int lrow = lane & 15, lk = lane >> 4;
  const f32x4 fzero = {0.f, 0.f, 0.f, 0.f};
  f32x4 acc[4][4];
  for (int a = 0; a < 4; ++a) for (int b = 0; b < 4; ++b) acc[a][b] = fzero;

  for (int k0 = 0; k0 < 512; k0 += 64) {
    __syncthreads();
    stage_tile<16>(A + (size_t)n0 * 512 + k0, 512, As, tid);
    stage_tile<16>(B + (size_t)e0 * 512 + k0, 512, Bs, tid);
    __syncthreads();
    for (int ks = 0; ks < 2; ++ks) {
      bf16x8 a[4], b[4];
      for (int f = 0; f < 4; ++f) {
        int r = wm * 64 + f * 16 + lrow;
        a[f] = *(const bf16x8*)(As + r * 64 + (((ks * 4 + lk) ^ (r & 7)) * 8));
      }
      for (int f = 0; f < 4; ++f) {
        int r = wn * 64 + f * 16 + lrow;
        b[f] = *(const bf16x8*)(Bs + r * 64 + (((ks * 4 + lk) ^ (r & 7)) * 8));
      }
      for (int fm = 0; fm < 4; ++fm)
        for (int fn = 0; fn < 4; ++fn)
          acc[fm][fn] = MFMA_B16(a[fm], b[fn], acc[fm][fn]);
    }
  }
  for (int fm = 0; fm < 4; ++fm)
    for (int fn = 0; fn < 4; ++fn)
      for (int r = 0; r < 4; ++r) {
        int n = n0 + wm * 64 + fm * 16 + lk * 4 + r;
        int e = e0 + wn * 64 + fn * 16 + lrow;
        size_t dstIdx = ((size_t)(((e >> 5) << 11) + n) << 8) + (h << 5) + (e & 31);
        out[dstIdx] = acc[fm][fn][r];
      }
}

extern "C" void kernel_launch(void* const* d_in, const int* in_sizes, int n_in,
                              void* d_out, int out_size, void* d_ws, size_t ws_size,
                              hipStream_t stream) {
  const float* x  = (const float*)d_in[0];
  const float* Wq = (const float*)d_in[1];
  const float* bq = (const float*)d_in[2];
  const float* Wk = (const float*)d_in[3];
  const float* bk = (const float*)d_in[4];
  const float* Wv = (const float*)d_in[5];
  const float* bv = (const float*)d_in[6];
  float* out  = (float*)d_out;
  float* attn = out + 8388608;

  char* ws = (char*)d_ws;
  u16*   xb    = (u16*)(ws);                      // 16,777,216 B
  u16*   Wb    = (u16*)(ws + 16777216);           //    393,216 B
  float* q_lin = (float*)(ws + 17170432);         // 33,554,432 B
  float* k_lin = (float*)(ws + 50724864);         // 33,554,432 B
  u16*   vT    = (u16*)(ws + 84279296);           // 16,777,216 B  (peak = 101,056,512 B)
  u16*   qb    = (u16*)(ws);                      // over xb   (dead after K1)
  u16*   kb    = (u16*)(ws + 17170432);           // over q_lin (dead after K2)
  u16*   kT    = (u16*)(ws + 33947648);
  u16*   ctxT  = (u16*)(ws + 50724864);           // over k_lin (dead after K3)
  float2* partials = (float2*)(attn + 33554432 - 131072);

  convert_kernel<<<8384, 256, 0, stream>>>(x, Wq, Wk, Wv, xb, Wb);
  linear_kernel<<<dim3(256, 12), 256, 0, stream>>>(xb, Wb, bq, bk, bv, q_lin, k_lin, vT);
  softmax_q_kernel<<<16384, 256, 0, stream>>>(q_lin, qb);
  softmax_k_part_kernel<<<dim3(8, 8, 16), 256, 0, stream>>>(k_lin, partials);
  softmax_k_norm_kernel<<<dim3(8, 8, 16), 256, 0, stream>>>(k_lin, partials, kb, kT);
  attn_kernel<<<dim3(16, 16, 8), 256, 0, stream>>>(qb, kb, attn);
  ctx_kernel<<<dim3(4, 4, 8), 256, 0, stream>>>(vT, kT, ctxT);
  out_kernel<<<dim3(16, 4, 8), 256, 0, stream>>>(qb, ctxT, out);
}